// Round 10
// baseline (1066.578 us; speedup 1.0000x reference)
//
#include <hip/hip_runtime.h>
#include <cmath>

#define D_IN 512
#define HC   512   // H1*C1 == H2*C2 == D_IN
#define NH1  8
#define NC1  64
#define NH2  4
#define NC2  128
#define BM 128
#define BN 128
#define BK 64

typedef __attribute__((ext_vector_type(8))) short short8;
typedef __attribute__((ext_vector_type(8))) unsigned short u16x8;
typedef __attribute__((ext_vector_type(8))) unsigned short ushort8;
typedef __attribute__((ext_vector_type(4))) float f32x4;

__device__ inline ushort f2bf(float f) {
  unsigned u = __float_as_uint(f);
  return (ushort)((u + 0x7FFFu + ((u >> 16) & 1u)) >> 16);
}
__device__ inline float bf2f(ushort b) { return __uint_as_float(((unsigned)b) << 16); }

// ---------- casts + W-tile-transpose + degree histogram in ONE launch ------
// W transpose: 64x64 LDS tiles, [64][65] pad, coalesced float4 in /
// ushort8 out. Block regions: [0,nxb) x-cast | [nxb,nxb+128) W | histogram.
__global__ void k_pre(const float* __restrict__ x, ushort* __restrict__ Abf,
                      const float* __restrict__ W1, const float* __restrict__ W2,
                      ushort* __restrict__ Wt1, ushort* __restrict__ Wt2, int n4x,
                      const int* __restrict__ ei, int E, int Etot,
                      int* __restrict__ cnt) {
  __shared__ float tl[64][65];
  int t = threadIdx.x;
  int bx = blockIdx.x;
  int nxb = (n4x + 255) >> 8;
  if (bx < nxb) {
    int i = bx * 256 + t;
    if (i < n4x) {
      float4 v = ((const float4*)x)[i];
      ushort4 r = { f2bf(v.x), f2bf(v.y), f2bf(v.z), f2bf(v.w) };
      ((ushort4*)Abf)[i] = r;
    }
  } else if (bx < nxb + 128) {
    int b = bx - nxb;
    int w = b >> 6, tile = b & 63;
    int k0 = (tile >> 3) * 64, n0 = (tile & 7) * 64;
    const float* W = w ? W2 : W1;
    ushort* Wt = w ? Wt2 : Wt1;
    int r = t >> 2, q = t & 3;
    const float4* src = (const float4*)(W + (size_t)(k0 + r) * HC + n0 + q * 16);
#pragma unroll
    for (int j = 0; j < 4; ++j) {
      float4 v = src[j];
      tl[r][q * 16 + 4 * j + 0] = v.x;
      tl[r][q * 16 + 4 * j + 1] = v.y;
      tl[r][q * 16 + 4 * j + 2] = v.z;
      tl[r][q * 16 + 4 * j + 3] = v.w;
    }
    __syncthreads();
    // Wt[n0+r][k0+q*16 .. +16) = W[k][n0+r] = tl[k-k0][r]
    ushort8* dst = (ushort8*)(Wt + (size_t)(n0 + r) * D_IN + k0 + q * 16);
#pragma unroll
    for (int j = 0; j < 2; ++j) {
      ushort8 o;
#pragma unroll
      for (int c = 0; c < 8; ++c) o[c] = f2bf(tl[q * 16 + 8 * j + c][r]);
      dst[j] = o;
    }
  } else {
    int e = (bx - nxb - 128) * 256 + t;
    if (e >= Etot) return;
    int d = (e < E) ? ei[E + e] : e - E;
    atomicAdd(&cnt[d], 1);
  }
}

// ---------- bf16 MFMA GEMM (R0 proven form) + fused scan block -------------
// Scan (R19 design, verified): two passes over cnt (2nd L2-hot), chunk sums
// in LDS reusing As/Bs, coalesced int4 loads, ~20 VGPR, no spills.
// Swizzle: chunked bijective XCD (FETCH 18.4->12.9MB, kept).
// GEMM LDS layout: slot s=(rowgrp)*4+kchunk, addr=(s*16+ln)*8 ushorts;
// ds_read stride-1 -> conflict-free. Do NOT trade occupancy/grid for
// traffic (BN=512 regressed 42->79).
// Att epilogue: node-major plain stores. H=8: asrc[row*H+h]. H=4: two
// partial slots [(row*4+h)*2+sub], sub=col64-idx.
template<int H, int SCAN>
__global__ void k_gemm_bf16(const ushort* __restrict__ A, const ushort* __restrict__ Bt,
                            ushort* __restrict__ Cbf,
                            const float* __restrict__ att_s, const float* __restrict__ att_d,
                            float* __restrict__ asrc, float* __restrict__ adst, int M,
                            const int* __restrict__ cnt, int* __restrict__ rowstart, int Nn) {
  constexpr int C = HC / H;
  __shared__ __align__(16) ushort As[BM * BK];   // 16 KB, two 8KB K-halves
  __shared__ __align__(16) ushort Bs[BN * BK];   // 16 KB
  int t = threadIdx.x;

  if (SCAN && blockIdx.x == 0) {
    // ---- two-pass LDS-chunked exclusive scan: cnt[0..Nn) -> rowstart ----
    int* sA = (int*)As;                       // 4096 ints
    int* sB = (int*)Bs;                       // chunks 4096.. + wsum at 3000
    int lane = t & 63, w = t >> 6;
    const int4* c4 = (const int4*)cnt;        // 16B-aligned (ws layout)
    int nb4 = (Nn + 3) >> 2;
    int T4 = (nb4 + 255) >> 8;                // chunks per thread
    if (T4 <= 20) {                           // Nn <= 20480
      for (int i = 0; i < T4; ++i) {
        int g = i * 256 + t;
        int s = 0;
        if (g < nb4) { int4 v = c4[g]; s = v.x + v.y + v.z + v.w; }
        (g < 4096 ? sA[g] : sB[g - 4096]) = s;
      }
      __syncthreads();
      int base = t * T4;
      int S = 0;
      for (int i = 0; i < T4; ++i) {
        int g = base + i;
        if (g < nb4) S += (g < 4096 ? sA[g] : sB[g - 4096]);
      }
      int v = S;
#pragma unroll
      for (int off = 1; off < 64; off <<= 1) {
        int u = __shfl_up(v, off);
        if (lane >= off) v += u;
      }
      if (lane == 63) sB[3000 + w] = v;
      __syncthreads();
      int wp = 0;
#pragma unroll
      for (int i = 0; i < 4; ++i) if (i < w) wp += sB[3000 + i];
      int run = wp + v - S;                   // exclusive prefix for this thread
      for (int i = 0; i < T4; ++i) {          // own cells only
        int g = base + i;
        if (g < nb4) {
          int c = (g < 4096 ? sA[g] : sB[g - 4096]);
          (g < 4096 ? sA[g] : sB[g - 4096]) = run;
          run += c;
        }
      }
      __syncthreads();
      for (int i = 0; i < T4; ++i) {
        int g = i * 256 + t;
        if (g < nb4) {
          int4 v = c4[g];
          int p = (g < 4096 ? sA[g] : sB[g - 4096]);
          int jb = g * 4;
          if (jb + 0 < Nn) rowstart[jb + 0] = p;  p += v.x;
          if (jb + 1 < Nn) rowstart[jb + 1] = p;  p += v.y;
          if (jb + 2 < Nn) rowstart[jb + 2] = p;  p += v.z;
          if (jb + 3 < Nn) rowstart[jb + 3] = p;  p += v.w;
          if (jb + 4 >= Nn) rowstart[Nn] = p;     // pads read zeroed cursor
        }
      }
    } else {
      int T = (Nn + 255) / 256;
      int base = t * T;
      int sum = 0;
      for (int i = 0; i < T; ++i) { int j = base + i; if (j < Nn) sum += cnt[j]; }
      int v = sum;
#pragma unroll
      for (int off = 1; off < 64; off <<= 1) {
        int u = __shfl_up(v, off);
        if (lane >= off) v += u;
      }
      if (lane == 63) sB[3000 + w] = v;
      __syncthreads();
      int wp = 0;
#pragma unroll
      for (int i = 0; i < 4; ++i) if (i < w) wp += sB[3000 + i];
      int run = wp + v - sum;
      for (int i = 0; i < T; ++i) {
        int j = base + i;
        if (j < Nn) { rowstart[j] = run; run += cnt[j]; }
      }
      if (t == 255) rowstart[Nn] = run;
    }
    return;
  }

  int lin = blockIdx.x - (SCAN ? 1 : 0);
  int nwg = gridDim.x - (SCAN ? 1 : 0);     // 628
  int q = nwg >> 3, r = nwg & 7;
  int xcd = lin & 7, pos = lin >> 3;
  int wg = (xcd < r ? xcd * (q + 1) : r * (q + 1) + (xcd - r) * q) + pos;
  int m0 = (wg >> 2) * BM;                  // 4 n-tiles per m-panel
  int n0 = (wg & 3) * BN;

  int wave = t >> 6, lane = t & 63;
  int ln = lane & 15, qd = lane >> 4;
  int wm = (wave >> 1) * 64, wn = (wave & 1) * 64;

  f32x4 acc[4][4] = {};

  int g = t >> 6, ct = (t >> 4) & 3, lt = t & 15;
  int rA0 = m0 + g * 16 + lt;      if (rA0 > M - 1) rA0 = M - 1;
  int rA1 = m0 + 64 + g * 16 + lt; if (rA1 > M - 1) rA1 = M - 1;
  const ushort* gA0 = A + (size_t)rA0 * D_IN + ct * 8;
  const ushort* gA1 = A + (size_t)rA1 * D_IN + ct * 8;
  const ushort* gB0 = Bt + (size_t)(n0 + g * 16 + lt) * D_IN + ct * 8;
  const ushort* gB1 = Bt + (size_t)(n0 + 64 + g * 16 + lt) * D_IN + ct * 8;

  for (int k0 = 0; k0 < D_IN; k0 += BK) {
    __syncthreads();
#pragma unroll
    for (int h = 0; h < 2; ++h) {
      int ko = k0 + h * 32;
      int lo = h * 4096;
      __builtin_amdgcn_global_load_lds(
          (const __attribute__((address_space(1))) void*)(gA0 + ko),
          (__attribute__((address_space(3))) void*)(As + lo + t * 8), 16, 0, 0);
      __builtin_amdgcn_global_load_lds(
          (const __attribute__((address_space(1))) void*)(gA1 + ko),
          (__attribute__((address_space(3))) void*)(As + lo + 2048 + t * 8), 16, 0, 0);
      __builtin_amdgcn_global_load_lds(
          (const __attribute__((address_space(1))) void*)(gB0 + ko),
          (__attribute__((address_space(3))) void*)(Bs + lo + t * 8), 16, 0, 0);
      __builtin_amdgcn_global_load_lds(
          (const __attribute__((address_space(1))) void*)(gB1 + ko),
          (__attribute__((address_space(3))) void*)(Bs + lo + 2048 + t * 8), 16, 0, 0);
    }
    __syncthreads();
#pragma unroll
    for (int h = 0; h < 2; ++h) {
      int lo = h * 4096;
      short8 a[4], bb[4];
#pragma unroll
      for (int i = 0; i < 4; ++i)
        a[i] = *(const short8*)&As[lo + (((wave >> 1) * 4 + i) * 4 + qd) * 128 + ln * 8];
#pragma unroll
      for (int j = 0; j < 4; ++j)
        bb[j] = *(const short8*)&Bs[lo + (((wave & 1) * 4 + j) * 4 + qd) * 128 + ln * 8];
#pragma unroll
      for (int i = 0; i < 4; ++i)
#pragma unroll
        for (int j = 0; j < 4; ++j)
          acc[i][j] = __builtin_amdgcn_mfma_f32_16x16x32_bf16(a[i], bb[j], acc[i][j], 0, 0, 0);
    }
  }

  // ---- C store (C/D layout: col = ln, row = qd*4 + reg) ----
#pragma unroll
  for (int i = 0; i < 4; ++i) {
#pragma unroll
    for (int reg = 0; reg < 4; ++reg) {
      int row = m0 + wm + i * 16 + qd * 4 + reg;
      if (row >= M) continue;
#pragma unroll
      for (int j = 0; j < 4; ++j)
        Cbf[(size_t)row * HC + n0 + wn + j * 16 + ln] = f2bf(acc[i][j][reg]);
    }
  }

  // ---- fused attention scores (plain stores only) ----
  int colbase = n0 + wn;         // multiple of 64
  int h = colbase / C;
  float sa[4], da[4];
#pragma unroll
  for (int j = 0; j < 4; ++j) {
    int c = (colbase % C) + j * 16 + ln;
    sa[j] = att_s[h * C + c];
    da[j] = att_d[h * C + c];
  }
#pragma unroll
  for (int i = 0; i < 4; ++i) {
#pragma unroll
    for (int reg = 0; reg < 4; ++reg) {
      float ps = acc[i][0][reg] * sa[0] + acc[i][1][reg] * sa[1]
               + acc[i][2][reg] * sa[2] + acc[i][3][reg] * sa[3];
      float pd = acc[i][0][reg] * da[0] + acc[i][1][reg] * da[1]
               + acc[i][2][reg] * da[2] + acc[i][3][reg] * da[3];
#pragma unroll
      for (int o = 1; o < 16; o <<= 1) { ps += __shfl_xor(ps, o); pd += __shfl_xor(pd, o); }
      int row = m0 + wm + i * 16 + qd * 4 + reg;
      if (ln == 0 && row < M) {
        if (C == 64) {
          asrc[row * H + h] = ps; adst[row * H + h] = pd;
        } else {
          int sub = (colbase >> 6) & 1;
          asrc[(row * H + h) * 2 + sub] = ps;
          adst[(row * H + h) * 2 + sub] = pd;
        }
      }
    }
  }
}

__global__ void k_scatter(const int* __restrict__ ei, int E, int Etot,
                          const int* __restrict__ rowstart, int* __restrict__ cursor,
                          int* __restrict__ csr_src) {
  int e = blockIdx.x * blockDim.x + threadIdx.x;
  if (e >= Etot) return;
  int s = (e < E) ? ei[e] : e - E;
  int d = (e < E) ? ei[E + e] : e - E;
  int pos = atomicAdd(&cursor[d], 1);
  csr_src[rowstart[d] + pos] = s;
}

// -------- layer-1 aggregation, ONE WAVE PER NODE, 4-way unroll -------------
// R23: STANDALONE kernel (was template<8,1>). R8's 4.6x agg regression
// showed rule-#19 codegen coupling between co-compiled instantiations
// (both gained SGPR 48 / LDS 512); splitting isolates agg1's codegen.
// Body is byte-identical to the R6/R9 MODE 1 path. 41.7us = random-line
// service-rate floor (3 structures identical; sliced variants regressed
// twice: R3 71.9, R7 104.6 — both VALU-bound).
__global__ void k_agg1(const int* __restrict__ rowstart, const int* __restrict__ csr_src,
                       const float* __restrict__ asrc, const float* __restrict__ adst,
                       const ushort* __restrict__ xp, ushort* __restrict__ hout,
                       const float* __restrict__ bias, int N) {
  int wv = threadIdx.x >> 6, lane = threadIdx.x & 63;
  int n = blockIdx.x * 4 + wv;
  if (n >= N) return;                         // wave-uniform
  int h = lane >> 3;                          // 8 chans/lane
  int beg = rowstart[n], end = rowstart[n + 1];

  float adn = adst[n * NH1 + h];

  float acc[8] = {};
  float wsum = 0.f;

#define SCR(s_)  (asrc[(s_) * NH1 + h])
#define EDGE(w_, a_)  do {                                   \
    float ww = (w_);                                         \
    _Pragma("unroll") for (int k = 0; k < 8; ++k)            \
      acc[k] += ww * bf2f((a_)[k]);                          \
    wsum += ww; } while (0)
#define LRELU(v_) ((v_) > 0.f ? (v_) : 0.2f * (v_))

  for (int c0 = beg; c0 < end; c0 += 64) {
    int len = end - c0; if (len > 64) len = 64;
    int ev = (lane < len) ? csr_src[c0 + lane] : 0;
    int j = 0;
    for (; j + 3 < len; j += 4) {
      int s0 = __shfl(ev, j), s1 = __shfl(ev, j + 1);
      int s2 = __shfl(ev, j + 2), s3 = __shfl(ev, j + 3);
      float v0 = SCR(s0) + adn, v1 = SCR(s1) + adn;
      float v2 = SCR(s2) + adn, v3 = SCR(s3) + adn;
      u16x8 a0 = ((const u16x8*)xp)[(size_t)s0 * 64 + lane];
      u16x8 a1 = ((const u16x8*)xp)[(size_t)s1 * 64 + lane];
      u16x8 a2 = ((const u16x8*)xp)[(size_t)s2 * 64 + lane];
      u16x8 a3 = ((const u16x8*)xp)[(size_t)s3 * 64 + lane];
      EDGE(__expf(LRELU(v0)), a0);
      EDGE(__expf(LRELU(v1)), a1);
      EDGE(__expf(LRELU(v2)), a2);
      EDGE(__expf(LRELU(v3)), a3);
    }
    for (; j + 1 < len; j += 2) {
      int s0 = __shfl(ev, j), s1 = __shfl(ev, j + 1);
      float v0 = SCR(s0) + adn, v1 = SCR(s1) + adn;
      u16x8 a0 = ((const u16x8*)xp)[(size_t)s0 * 64 + lane];
      u16x8 a1 = ((const u16x8*)xp)[(size_t)s1 * 64 + lane];
      EDGE(__expf(LRELU(v0)), a0);
      EDGE(__expf(LRELU(v1)), a1);
    }
    if (j < len) {
      int s0 = __shfl(ev, j);
      float v0 = SCR(s0) + adn;
      u16x8 a0 = ((const u16x8*)xp)[(size_t)s0 * 64 + lane];
      EDGE(__expf(LRELU(v0)), a0);
    }
  }
#undef SCR

  float rdn = 1.0f / (wsum + 1e-16f);
#pragma unroll
  for (int k = 0; k < 8; ++k) acc[k] *= rdn;

  int c = lane * 8;
  u16x8 rr;
#pragma unroll
  for (int k = 0; k < 8; ++k) {
    float v = acc[k] + bias[c + k];
    v = (v > 0.f) ? v : expm1f(v);
    rr[k] = f2bf(v);
  }
  ((u16x8*)hout)[(size_t)n * 64 + lane] = rr;
#undef EDGE
#undef LRELU
}

// -------- layer-2 aggregation + fused loss finalize (R23) ------------------
// Standalone kernel (rule #19). Body identical to R6/R9 MODE 2 path; the
// finalize is an APPENDED per-wave tail: no __syncthreads, no LDS, no
// wrapper around the gather loop (each R8 hazard removed). Every wave owns
// one node n<N and bumps syncv[0] after threadfence; the wave that sees
// arrived==N reduces acc2[256] with 4 atomic-reads/lane + 64-lane butterfly
// and writes out0. Falsifier: if this agg >60us, the counter/finalize IS
// the R8 mechanism -> revert permanently, declare structural roofline.
__global__ void k_agg2(const int* __restrict__ rowstart, const int* __restrict__ csr_src,
                       const float* __restrict__ asrc, const float* __restrict__ adst,
                       const ushort* __restrict__ xp,
                       float* __restrict__ out2, const float* __restrict__ bias,
                       const int* __restrict__ y, const int* __restrict__ msk,
                       float* __restrict__ acc2, int N,
                       float* __restrict__ out0, int* __restrict__ syncv) {
  constexpr int H = NH2;
  int wv = threadIdx.x >> 6, lane = threadIdx.x & 63;
  int n = blockIdx.x * 4 + wv;
  if (n >= N) return;                         // wave-uniform
  int h = lane >> 4;                          // 8 chans/lane
  int beg = rowstart[n], end = rowstart[n + 1];

  float2 t2 = ((const float2*)adst)[n * H + h];
  float adn = t2.x + t2.y;

  float acc[8] = {};
  float wsum = 0.f;

#define SCR(s_)  (((const float2*)asrc)[(s_) * H + h].x + \
                  ((const float2*)asrc)[(s_) * H + h].y)
#define EDGE(w_, a_)  do {                                   \
    float ww = (w_);                                         \
    _Pragma("unroll") for (int k = 0; k < 8; ++k)            \
      acc[k] += ww * bf2f((a_)[k]);                          \
    wsum += ww; } while (0)
#define LRELU(v_) ((v_) > 0.f ? (v_) : 0.2f * (v_))

  for (int c0 = beg; c0 < end; c0 += 64) {
    int len = end - c0; if (len > 64) len = 64;
    int ev = (lane < len) ? csr_src[c0 + lane] : 0;
    int j = 0;
    for (; j + 3 < len; j += 4) {
      int s0 = __shfl(ev, j), s1 = __shfl(ev, j + 1);
      int s2 = __shfl(ev, j + 2), s3 = __shfl(ev, j + 3);
      float v0 = SCR(s0) + adn, v1 = SCR(s1) + adn;
      float v2 = SCR(s2) + adn, v3 = SCR(s3) + adn;
      u16x8 a0 = ((const u16x8*)xp)[(size_t)s0 * 64 + lane];
      u16x8 a1 = ((const u16x8*)xp)[(size_t)s1 * 64 + lane];
      u16x8 a2 = ((const u16x8*)xp)[(size_t)s2 * 64 + lane];
      u16x8 a3 = ((const u16x8*)xp)[(size_t)s3 * 64 + lane];
      EDGE(__expf(LRELU(v0)), a0);
      EDGE(__expf(LRELU(v1)), a1);
      EDGE(__expf(LRELU(v2)), a2);
      EDGE(__expf(LRELU(v3)), a3);
    }
    for (; j + 1 < len; j += 2) {
      int s0 = __shfl(ev, j), s1 = __shfl(ev, j + 1);
      float v0 = SCR(s0) + adn, v1 = SCR(s1) + adn;
      u16x8 a0 = ((const u16x8*)xp)[(size_t)s0 * 64 + lane];
      u16x8 a1 = ((const u16x8*)xp)[(size_t)s1 * 64 + lane];
      EDGE(__expf(LRELU(v0)), a0);
      EDGE(__expf(LRELU(v1)), a1);
    }
    if (j < len) {
      int s0 = __shfl(ev, j);
      float v0 = SCR(s0) + adn;
      u16x8 a0 = ((const u16x8*)xp)[(size_t)s0 * 64 + lane];
      EDGE(__expf(LRELU(v0)), a0);
    }
  }
#undef SCR
#undef EDGE
#undef LRELU

  float rdn = 1.0f / (wsum + 1e-16f);
#pragma unroll
  for (int k = 0; k < 8; ++k) acc[k] *= rdn;

  // head-mean: channel c'=(lane&15)*8+k lives on lanes {l, l^16, l^32, l^48}
#pragma unroll
  for (int k = 0; k < 8; ++k) {
    float v = acc[k];
    v += __shfl_xor(v, 16);
    v += __shfl_xor(v, 32);
    acc[k] = v * 0.25f + bias[(lane & 15) * 8 + k];
  }
  if (lane < 16) {       // scalar stores: out2 = out+1 is only 4B-aligned
    int cb = lane * 8;
#pragma unroll
    for (int k = 0; k < 8; ++k) out2[(size_t)n * NC2 + cb + k] = acc[k];
  }
  // fused CE: lanes 0..15 hold the 128 logits (copies in upper 48 lanes)
  float mx = acc[0];
#pragma unroll
  for (int k = 1; k < 8; ++k) mx = fmaxf(mx, acc[k]);
#pragma unroll
  for (int o = 1; o < 16; o <<= 1) mx = fmaxf(mx, __shfl_xor(mx, o));
  float e = 0.f;
#pragma unroll
  for (int k = 0; k < 8; ++k) e += __expf(acc[k] - mx);
#pragma unroll
  for (int o = 1; o < 16; o <<= 1) e += __shfl_xor(e, o);
  int yv = y[n];
  float sel = acc[0];
#pragma unroll
  for (int k = 1; k < 8; ++k) sel = ((yv & 7) == k) ? acc[k] : sel;
  float vy = __shfl(sel, yv >> 3);
  if (lane == 0 && msk[n] != 0) {
    float ce = mx + logf(e) - vy;
    int slot = n & 127;
    atomicAdd(&acc2[slot], ce);
    atomicAdd(&acc2[128 + slot], 1.0f);
  }

  // ---- appended per-wave tail: last arriving wave finalizes the loss ----
  __threadfence();                            // CE atomics visible device-wide
  int arrived = 0;
  if (lane == 0) arrived = atomicAdd(&syncv[0], 1) + 1;
  arrived = __shfl(arrived, 0);
  if (arrived == N) {                         // exactly one wave sees this
    float ce = atomicAdd(&acc2[lane], 0.0f) + atomicAdd(&acc2[64 + lane], 0.0f);
    float ct = atomicAdd(&acc2[128 + lane], 0.0f) + atomicAdd(&acc2[192 + lane], 0.0f);
#pragma unroll
    for (int o = 32; o > 0; o >>= 1) { ce += __shfl_xor(ce, o); ct += __shfl_xor(ct, o); }
    if (lane == 0) out0[0] = ce / ct;
  }
}

extern "C" void kernel_launch(void* const* d_in, const int* in_sizes, int n_in,
                              void* d_out, int out_size, void* d_ws, size_t ws_size,
                              hipStream_t stream) {
  const float* x   = (const float*)d_in[0];
  const int*   ei  = (const int*)d_in[1];
  const int*   y   = (const int*)d_in[2];
  const int*   msk = (const int*)d_in[3];
  const float* W1  = (const float*)d_in[4];
  const float* as1 = (const float*)d_in[5];
  const float* ad1 = (const float*)d_in[6];
  const float* b1  = (const float*)d_in[7];
  const float* W2  = (const float*)d_in[8];
  const float* as2 = (const float*)d_in[9];
  const float* ad2 = (const float*)d_in[10];
  const float* b2  = (const float*)d_in[11];
  float* out = (float*)d_out;

  int N = in_sizes[0] / D_IN;   // 20000
  int E = in_sizes[1] / 2;      // 100000
  int Etot = E + N;             // 120000 (self-loops appended)

  float* ws = (float*)d_ws;
  size_t NF = (size_t)N * HC;
  float* asr1 = ws;                       // N*8  (plain-written in GEMM1)
  float* adt1 = asr1 + (size_t)N * NH1;   // N*8
  float* asr2 = adt1 + (size_t)N * NH1;   // N*8  (partials, plain-written GEMM2)
  float* adt2 = asr2 + (size_t)N * 2 * NH2; // N*8
  // ---- zero-init region: acc2, syncv, cnt, cursor (contiguous) ----
  float* acc2 = adt2 + (size_t)N * 2 * NH2; // 256
  int*   syncv  = (int*)(acc2 + 256);     // 16 ([0]=agg2 wave counter)
  int*   cnt    = syncv + 16;             // N (16B-aligned: offsets all x16)
  int*   cursor = cnt + N;                // N (zeroed; pads scan's int4 tail)
  size_t zero_bytes = (256 + 16 + 2 * (size_t)N) * sizeof(float);
  // ---- fully-written region ----
  int*   rowstart = cursor + N;           // N+1
  int*   csr_src  = rowstart + N + 1;     // Etot
  ushort* xpbf = (ushort*)((((uintptr_t)(csr_src + Etot)) + 15) & ~(uintptr_t)15);
  ushort* Abf = xpbf + NF;                // N*512
  ushort* Wt1 = Abf + NF;                 // 512*512
  ushort* Wt2 = Wt1 + (size_t)D_IN * HC;  // 512*512

  hipMemsetAsync(acc2, 0, zero_bytes, stream);

  // casts (x) + W tile-transpose + degree histogram in one launch
  int n4x = (int)(NF / 4);
  int nxb = (n4x + 255) / 256;
  int nhb = (Etot + 255) / 256;
  k_pre<<<nxb + 128 + nhb, 256, 0, stream>>>(x, Abf, W1, W2, Wt1, Wt2, n4x,
                                             ei, E, Etot, cnt);

  int nwg = (HC / BN) * ((N + BM - 1) / BM);  // 628
  int aggblocks = (N + 3) / 4;                // 4 nodes (waves) per block

  // ---- layer 1: gemm (blocks 1..628) + CSR scan (block 0) in one launch ----
  k_gemm_bf16<NH1, 1><<<nwg + 1, 256, 0, stream>>>(Abf, Wt1, xpbf, as1, ad1, asr1, adt1, N,
                                                   cnt, rowstart, N);
  k_scatter<<<(Etot + 255) / 256, 256, 0, stream>>>(ei, E, Etot, rowstart, cursor, csr_src);
  k_agg1<<<aggblocks, 256, 0, stream>>>(rowstart, csr_src, asr1, adt1, xpbf, Abf, b1, N);

  // ---- layer 2 (agg2 fuses the loss finalize in its last wave) ----
  k_gemm_bf16<NH2, 0><<<nwg, 256, 0, stream>>>(Abf, Wt2, xpbf, as2, ad2, asr2, adt2, N,
                                               nullptr, nullptr, N);
  k_agg2<<<aggblocks, 256, 0, stream>>>(rowstart, csr_src, asr2, adt2, xpbf,
                                        out + 1, b2, y, msk, acc2, N,
                                        out, syncv);
}

// Round 11
// 267.977 us; speedup vs baseline: 3.9801x; 3.9801x over previous
//
#include <hip/hip_runtime.h>
#include <cmath>

#define D_IN 512
#define HC   512   // H1*C1 == H2*C2 == D_IN
#define NH1  8
#define NC1  64
#define NH2  4
#define NC2  128
#define BM 128
#define BN 128
#define BK 64

typedef __attribute__((ext_vector_type(8))) short short8;
typedef __attribute__((ext_vector_type(8))) unsigned short u16x8;
typedef __attribute__((ext_vector_type(8))) unsigned short ushort8;
typedef __attribute__((ext_vector_type(4))) float f32x4;

__device__ inline ushort f2bf(float f) {
  unsigned u = __float_as_uint(f);
  return (ushort)((u + 0x7FFFu + ((u >> 16) & 1u)) >> 16);
}
__device__ inline float bf2f(ushort b) { return __uint_as_float(((unsigned)b) << 16); }

// ---------- casts + W-tile-transpose + degree histogram in ONE launch ------
// R24: exact revert to the R6/R9 structure (266.0 / 268.2 us, reproduced).
// SESSION LEDGER of abandoned levers (do NOT retry):
//  - agg channel-slicing: R3 71.9us, R7 104.6us (VALU-bound both times)
//  - device-scope sync fusion: R8 flags (agg 190us), R10 per-wave
//    __threadfence()+counter tail (agg2 886us — fence per wave serializes
//    against all outstanding traffic; 20K RMWs on one line)
//  - GEMM counted-vmcnt pipelines: R14/R15 neutral-to-regressed (20ms outlier)
// W transpose: 64x64 LDS tiles, [64][65] pad, coalesced float4 in /
// ushort8 out. Block regions: [0,nxb) x-cast | [nxb,nxb+128) W | histogram.
__global__ void k_pre(const float* __restrict__ x, ushort* __restrict__ Abf,
                      const float* __restrict__ W1, const float* __restrict__ W2,
                      ushort* __restrict__ Wt1, ushort* __restrict__ Wt2, int n4x,
                      const int* __restrict__ ei, int E, int Etot,
                      int* __restrict__ cnt) {
  __shared__ float tl[64][65];
  int t = threadIdx.x;
  int bx = blockIdx.x;
  int nxb = (n4x + 255) >> 8;
  if (bx < nxb) {
    int i = bx * 256 + t;
    if (i < n4x) {
      float4 v = ((const float4*)x)[i];
      ushort4 r = { f2bf(v.x), f2bf(v.y), f2bf(v.z), f2bf(v.w) };
      ((ushort4*)Abf)[i] = r;
    }
  } else if (bx < nxb + 128) {
    int b = bx - nxb;
    int w = b >> 6, tile = b & 63;
    int k0 = (tile >> 3) * 64, n0 = (tile & 7) * 64;
    const float* W = w ? W2 : W1;
    ushort* Wt = w ? Wt2 : Wt1;
    int r = t >> 2, q = t & 3;
    const float4* src = (const float4*)(W + (size_t)(k0 + r) * HC + n0 + q * 16);
#pragma unroll
    for (int j = 0; j < 4; ++j) {
      float4 v = src[j];
      tl[r][q * 16 + 4 * j + 0] = v.x;
      tl[r][q * 16 + 4 * j + 1] = v.y;
      tl[r][q * 16 + 4 * j + 2] = v.z;
      tl[r][q * 16 + 4 * j + 3] = v.w;
    }
    __syncthreads();
    // Wt[n0+r][k0+q*16 .. +16) = W[k][n0+r] = tl[k-k0][r]
    ushort8* dst = (ushort8*)(Wt + (size_t)(n0 + r) * D_IN + k0 + q * 16);
#pragma unroll
    for (int j = 0; j < 2; ++j) {
      ushort8 o;
#pragma unroll
      for (int c = 0; c < 8; ++c) o[c] = f2bf(tl[q * 16 + 8 * j + c][r]);
      dst[j] = o;
    }
  } else {
    int e = (bx - nxb - 128) * 256 + t;
    if (e >= Etot) return;
    int d = (e < E) ? ei[E + e] : e - E;
    atomicAdd(&cnt[d], 1);
  }
}

// ---------- bf16 MFMA GEMM (R0 proven form) + fused scan block -------------
// Scan (R19 design, verified): two passes over cnt (2nd L2-hot), chunk sums
// in LDS reusing As/Bs, coalesced int4 loads, ~20 VGPR, no spills.
// Swizzle: chunked bijective XCD (FETCH 18.4->12.9MB, kept).
// GEMM LDS layout: slot s=(rowgrp)*4+kchunk, addr=(s*16+ln)*8 ushorts;
// ds_read stride-1 -> conflict-free. Do NOT trade occupancy/grid for
// traffic (BN=512 regressed 42->79).
// Att epilogue: node-major plain stores. H=8: asrc[row*H+h]. H=4: two
// partial slots [(row*4+h)*2+sub], sub=col64-idx.
template<int H, int SCAN>
__global__ void k_gemm_bf16(const ushort* __restrict__ A, const ushort* __restrict__ Bt,
                            ushort* __restrict__ Cbf,
                            const float* __restrict__ att_s, const float* __restrict__ att_d,
                            float* __restrict__ asrc, float* __restrict__ adst, int M,
                            const int* __restrict__ cnt, int* __restrict__ rowstart, int Nn) {
  constexpr int C = HC / H;
  __shared__ __align__(16) ushort As[BM * BK];   // 16 KB, two 8KB K-halves
  __shared__ __align__(16) ushort Bs[BN * BK];   // 16 KB
  int t = threadIdx.x;

  if (SCAN && blockIdx.x == 0) {
    // ---- two-pass LDS-chunked exclusive scan: cnt[0..Nn) -> rowstart ----
    int* sA = (int*)As;                       // 4096 ints
    int* sB = (int*)Bs;                       // chunks 4096.. + wsum at 3000
    int lane = t & 63, w = t >> 6;
    const int4* c4 = (const int4*)cnt;        // 16B-aligned (ws layout)
    int nb4 = (Nn + 3) >> 2;
    int T4 = (nb4 + 255) >> 8;                // chunks per thread
    if (T4 <= 20) {                           // Nn <= 20480
      for (int i = 0; i < T4; ++i) {
        int g = i * 256 + t;
        int s = 0;
        if (g < nb4) { int4 v = c4[g]; s = v.x + v.y + v.z + v.w; }
        (g < 4096 ? sA[g] : sB[g - 4096]) = s;
      }
      __syncthreads();
      int base = t * T4;
      int S = 0;
      for (int i = 0; i < T4; ++i) {
        int g = base + i;
        if (g < nb4) S += (g < 4096 ? sA[g] : sB[g - 4096]);
      }
      int v = S;
#pragma unroll
      for (int off = 1; off < 64; off <<= 1) {
        int u = __shfl_up(v, off);
        if (lane >= off) v += u;
      }
      if (lane == 63) sB[3000 + w] = v;
      __syncthreads();
      int wp = 0;
#pragma unroll
      for (int i = 0; i < 4; ++i) if (i < w) wp += sB[3000 + i];
      int run = wp + v - S;                   // exclusive prefix for this thread
      for (int i = 0; i < T4; ++i) {          // own cells only
        int g = base + i;
        if (g < nb4) {
          int c = (g < 4096 ? sA[g] : sB[g - 4096]);
          (g < 4096 ? sA[g] : sB[g - 4096]) = run;
          run += c;
        }
      }
      __syncthreads();
      for (int i = 0; i < T4; ++i) {
        int g = i * 256 + t;
        if (g < nb4) {
          int4 v = c4[g];
          int p = (g < 4096 ? sA[g] : sB[g - 4096]);
          int jb = g * 4;
          if (jb + 0 < Nn) rowstart[jb + 0] = p;  p += v.x;
          if (jb + 1 < Nn) rowstart[jb + 1] = p;  p += v.y;
          if (jb + 2 < Nn) rowstart[jb + 2] = p;  p += v.z;
          if (jb + 3 < Nn) rowstart[jb + 3] = p;  p += v.w;
          if (jb + 4 >= Nn) rowstart[Nn] = p;     // pads read zeroed cursor
        }
      }
    } else {
      int T = (Nn + 255) / 256;
      int base = t * T;
      int sum = 0;
      for (int i = 0; i < T; ++i) { int j = base + i; if (j < Nn) sum += cnt[j]; }
      int v = sum;
#pragma unroll
      for (int off = 1; off < 64; off <<= 1) {
        int u = __shfl_up(v, off);
        if (lane >= off) v += u;
      }
      if (lane == 63) sB[3000 + w] = v;
      __syncthreads();
      int wp = 0;
#pragma unroll
      for (int i = 0; i < 4; ++i) if (i < w) wp += sB[3000 + i];
      int run = wp + v - sum;
      for (int i = 0; i < T; ++i) {
        int j = base + i;
        if (j < Nn) { rowstart[j] = run; run += cnt[j]; }
      }
      if (t == 255) rowstart[Nn] = run;
    }
    return;
  }

  int lin = blockIdx.x - (SCAN ? 1 : 0);
  int nwg = gridDim.x - (SCAN ? 1 : 0);     // 628
  int q = nwg >> 3, r = nwg & 7;
  int xcd = lin & 7, pos = lin >> 3;
  int wg = (xcd < r ? xcd * (q + 1) : r * (q + 1) + (xcd - r) * q) + pos;
  int m0 = (wg >> 2) * BM;                  // 4 n-tiles per m-panel
  int n0 = (wg & 3) * BN;

  int wave = t >> 6, lane = t & 63;
  int ln = lane & 15, qd = lane >> 4;
  int wm = (wave >> 1) * 64, wn = (wave & 1) * 64;

  f32x4 acc[4][4] = {};

  int g = t >> 6, ct = (t >> 4) & 3, lt = t & 15;
  int rA0 = m0 + g * 16 + lt;      if (rA0 > M - 1) rA0 = M - 1;
  int rA1 = m0 + 64 + g * 16 + lt; if (rA1 > M - 1) rA1 = M - 1;
  const ushort* gA0 = A + (size_t)rA0 * D_IN + ct * 8;
  const ushort* gA1 = A + (size_t)rA1 * D_IN + ct * 8;
  const ushort* gB0 = Bt + (size_t)(n0 + g * 16 + lt) * D_IN + ct * 8;
  const ushort* gB1 = Bt + (size_t)(n0 + 64 + g * 16 + lt) * D_IN + ct * 8;

  for (int k0 = 0; k0 < D_IN; k0 += BK) {
    __syncthreads();
#pragma unroll
    for (int h = 0; h < 2; ++h) {
      int ko = k0 + h * 32;
      int lo = h * 4096;
      __builtin_amdgcn_global_load_lds(
          (const __attribute__((address_space(1))) void*)(gA0 + ko),
          (__attribute__((address_space(3))) void*)(As + lo + t * 8), 16, 0, 0);
      __builtin_amdgcn_global_load_lds(
          (const __attribute__((address_space(1))) void*)(gA1 + ko),
          (__attribute__((address_space(3))) void*)(As + lo + 2048 + t * 8), 16, 0, 0);
      __builtin_amdgcn_global_load_lds(
          (const __attribute__((address_space(1))) void*)(gB0 + ko),
          (__attribute__((address_space(3))) void*)(Bs + lo + t * 8), 16, 0, 0);
      __builtin_amdgcn_global_load_lds(
          (const __attribute__((address_space(1))) void*)(gB1 + ko),
          (__attribute__((address_space(3))) void*)(Bs + lo + 2048 + t * 8), 16, 0, 0);
    }
    __syncthreads();
#pragma unroll
    for (int h = 0; h < 2; ++h) {
      int lo = h * 4096;
      short8 a[4], bb[4];
#pragma unroll
      for (int i = 0; i < 4; ++i)
        a[i] = *(const short8*)&As[lo + (((wave >> 1) * 4 + i) * 4 + qd) * 128 + ln * 8];
#pragma unroll
      for (int j = 0; j < 4; ++j)
        bb[j] = *(const short8*)&Bs[lo + (((wave & 1) * 4 + j) * 4 + qd) * 128 + ln * 8];
#pragma unroll
      for (int i = 0; i < 4; ++i)
#pragma unroll
        for (int j = 0; j < 4; ++j)
          acc[i][j] = __builtin_amdgcn_mfma_f32_16x16x32_bf16(a[i], bb[j], acc[i][j], 0, 0, 0);
    }
  }

  // ---- C store (C/D layout: col = ln, row = qd*4 + reg) ----
#pragma unroll
  for (int i = 0; i < 4; ++i) {
#pragma unroll
    for (int reg = 0; reg < 4; ++reg) {
      int row = m0 + wm + i * 16 + qd * 4 + reg;
      if (row >= M) continue;
#pragma unroll
      for (int j = 0; j < 4; ++j)
        Cbf[(size_t)row * HC + n0 + wn + j * 16 + ln] = f2bf(acc[i][j][reg]);
    }
  }

  // ---- fused attention scores (plain stores only) ----
  int colbase = n0 + wn;         // multiple of 64
  int h = colbase / C;
  float sa[4], da[4];
#pragma unroll
  for (int j = 0; j < 4; ++j) {
    int c = (colbase % C) + j * 16 + ln;
    sa[j] = att_s[h * C + c];
    da[j] = att_d[h * C + c];
  }
#pragma unroll
  for (int i = 0; i < 4; ++i) {
#pragma unroll
    for (int reg = 0; reg < 4; ++reg) {
      float ps = acc[i][0][reg] * sa[0] + acc[i][1][reg] * sa[1]
               + acc[i][2][reg] * sa[2] + acc[i][3][reg] * sa[3];
      float pd = acc[i][0][reg] * da[0] + acc[i][1][reg] * da[1]
               + acc[i][2][reg] * da[2] + acc[i][3][reg] * da[3];
#pragma unroll
      for (int o = 1; o < 16; o <<= 1) { ps += __shfl_xor(ps, o); pd += __shfl_xor(pd, o); }
      int row = m0 + wm + i * 16 + qd * 4 + reg;
      if (ln == 0 && row < M) {
        if (C == 64) {
          asrc[row * H + h] = ps; adst[row * H + h] = pd;
        } else {
          int sub = (colbase >> 6) & 1;
          asrc[(row * H + h) * 2 + sub] = ps;
          adst[(row * H + h) * 2 + sub] = pd;
        }
      }
    }
  }
}

__global__ void k_scatter(const int* __restrict__ ei, int E, int Etot,
                          const int* __restrict__ rowstart, int* __restrict__ cursor,
                          int* __restrict__ csr_src) {
  int e = blockIdx.x * blockDim.x + threadIdx.x;
  if (e >= Etot) return;
  int s = (e < E) ? ei[e] : e - E;
  int d = (e < E) ? ei[E + e] : e - E;
  int pos = atomicAdd(&cursor[d], 1);
  csr_src[rowstart[d] + pos] = s;
}

// -------- gather aggregation, ONE WAVE PER NODE, 4-way unroll --------------
// 41.7us = random-line service-rate floor (3 structures identical; sliced
// variants regressed twice: R3 71.9, R7 104.6 — both VALU-bound).
// MODE 1 (H=8): scores at [x*H+h]; hout = bf16(elu(sum/den + b)).
// MODE 2 (H=4): scores are 2 partials at [(x*H+h)*2+{0,1}];
//   head-mean via shfl_xor(16,32) fold; fused CE via 16-lane butterflies.
template<int H, int MODE>
__global__ void k_agg(const int* __restrict__ rowstart, const int* __restrict__ csr_src,
                      const float* __restrict__ asrc, const float* __restrict__ adst,
                      const ushort* __restrict__ xp, ushort* __restrict__ hout,
                      float* __restrict__ out2, const float* __restrict__ bias,
                      const int* __restrict__ y, const int* __restrict__ msk,
                      float* __restrict__ acc2, int N) {
  int wv = threadIdx.x >> 6, lane = threadIdx.x & 63;
  int n = blockIdx.x * 4 + wv;
  if (n >= N) return;                         // wave-uniform
  int h = (MODE == 1) ? (lane >> 3) : (lane >> 4);   // 8 chans/lane
  int beg = rowstart[n], end = rowstart[n + 1];

  float adn;
  if (MODE == 1) adn = adst[n * H + h];
  else { float2 t2 = ((const float2*)adst)[n * H + h]; adn = t2.x + t2.y; }

  float acc[8] = {};
  float wsum = 0.f;

#define SCR(s_)  ((MODE == 1) ? asrc[(s_) * H + h] \
                   : (((const float2*)asrc)[(s_) * H + h].x + \
                      ((const float2*)asrc)[(s_) * H + h].y))
#define EDGE(w_, a_)  do {                                   \
    float ww = (w_);                                         \
    _Pragma("unroll") for (int k = 0; k < 8; ++k)            \
      acc[k] += ww * bf2f((a_)[k]);                          \
    wsum += ww; } while (0)
#define LRELU(v_) ((v_) > 0.f ? (v_) : 0.2f * (v_))

  for (int c0 = beg; c0 < end; c0 += 64) {
    int len = end - c0; if (len > 64) len = 64;
    int ev = (lane < len) ? csr_src[c0 + lane] : 0;
    int j = 0;
    for (; j + 3 < len; j += 4) {
      int s0 = __shfl(ev, j), s1 = __shfl(ev, j + 1);
      int s2 = __shfl(ev, j + 2), s3 = __shfl(ev, j + 3);
      float v0 = SCR(s0) + adn, v1 = SCR(s1) + adn;
      float v2 = SCR(s2) + adn, v3 = SCR(s3) + adn;
      u16x8 a0 = ((const u16x8*)xp)[(size_t)s0 * 64 + lane];
      u16x8 a1 = ((const u16x8*)xp)[(size_t)s1 * 64 + lane];
      u16x8 a2 = ((const u16x8*)xp)[(size_t)s2 * 64 + lane];
      u16x8 a3 = ((const u16x8*)xp)[(size_t)s3 * 64 + lane];
      EDGE(__expf(LRELU(v0)), a0);
      EDGE(__expf(LRELU(v1)), a1);
      EDGE(__expf(LRELU(v2)), a2);
      EDGE(__expf(LRELU(v3)), a3);
    }
    for (; j + 1 < len; j += 2) {
      int s0 = __shfl(ev, j), s1 = __shfl(ev, j + 1);
      float v0 = SCR(s0) + adn, v1 = SCR(s1) + adn;
      u16x8 a0 = ((const u16x8*)xp)[(size_t)s0 * 64 + lane];
      u16x8 a1 = ((const u16x8*)xp)[(size_t)s1 * 64 + lane];
      EDGE(__expf(LRELU(v0)), a0);
      EDGE(__expf(LRELU(v1)), a1);
    }
    if (j < len) {
      int s0 = __shfl(ev, j);
      float v0 = SCR(s0) + adn;
      u16x8 a0 = ((const u16x8*)xp)[(size_t)s0 * 64 + lane];
      EDGE(__expf(LRELU(v0)), a0);
    }
  }
#undef SCR
#undef EDGE
#undef LRELU

  float rdn = 1.0f / (wsum + 1e-16f);
#pragma unroll
  for (int k = 0; k < 8; ++k) acc[k] *= rdn;

  if (MODE == 1) {
    int c = lane * 8;
    u16x8 rr;
#pragma unroll
    for (int k = 0; k < 8; ++k) {
      float v = acc[k] + bias[c + k];
      v = (v > 0.f) ? v : expm1f(v);
      rr[k] = f2bf(v);
    }
    ((u16x8*)hout)[(size_t)n * 64 + lane] = rr;
  } else {
    // head-mean: channel c'=(lane&15)*8+k lives on lanes {l, l^16, l^32, l^48}
#pragma unroll
    for (int k = 0; k < 8; ++k) {
      float v = acc[k];
      v += __shfl_xor(v, 16);
      v += __shfl_xor(v, 32);
      acc[k] = v * 0.25f + bias[(lane & 15) * 8 + k];
    }
    if (lane < 16) {       // scalar stores: out2 = out+1 is only 4B-aligned
      int cb = lane * 8;
#pragma unroll
      for (int k = 0; k < 8; ++k) out2[(size_t)n * NC2 + cb + k] = acc[k];
    }
    // fused CE: lanes 0..15 hold the 128 logits (copies in upper 48 lanes)
    float mx = acc[0];
#pragma unroll
    for (int k = 1; k < 8; ++k) mx = fmaxf(mx, acc[k]);
#pragma unroll
    for (int o = 1; o < 16; o <<= 1) mx = fmaxf(mx, __shfl_xor(mx, o));
    float e = 0.f;
#pragma unroll
    for (int k = 0; k < 8; ++k) e += __expf(acc[k] - mx);
#pragma unroll
    for (int o = 1; o < 16; o <<= 1) e += __shfl_xor(e, o);
    int yv = y[n];
    float sel = acc[0];
#pragma unroll
    for (int k = 1; k < 8; ++k) sel = ((yv & 7) == k) ? acc[k] : sel;
    float vy = __shfl(sel, yv >> 3);
    if (lane == 0 && msk[n] != 0) {
      float ce = mx + logf(e) - vy;
      int slot = n & 127;
      atomicAdd(&acc2[slot], ce);
      atomicAdd(&acc2[128 + slot], 1.0f);
    }
  }
}

__global__ void k_final(const float* __restrict__ acc2, float* __restrict__ out0) {
  int tid = threadIdx.x;   // 128 threads
  float ce = acc2[tid], ct = acc2[128 + tid];
#pragma unroll
  for (int o = 32; o > 0; o >>= 1) { ce += __shfl_xor(ce, o); ct += __shfl_xor(ct, o); }
  __shared__ float s[4];
  if ((tid & 63) == 0) { s[(tid >> 6) * 2] = ce; s[(tid >> 6) * 2 + 1] = ct; }
  __syncthreads();
  if (tid == 0) out0[0] = (s[0] + s[2]) / (s[1] + s[3]);
}

extern "C" void kernel_launch(void* const* d_in, const int* in_sizes, int n_in,
                              void* d_out, int out_size, void* d_ws, size_t ws_size,
                              hipStream_t stream) {
  const float* x   = (const float*)d_in[0];
  const int*   ei  = (const int*)d_in[1];
  const int*   y   = (const int*)d_in[2];
  const int*   msk = (const int*)d_in[3];
  const float* W1  = (const float*)d_in[4];
  const float* as1 = (const float*)d_in[5];
  const float* ad1 = (const float*)d_in[6];
  const float* b1  = (const float*)d_in[7];
  const float* W2  = (const float*)d_in[8];
  const float* as2 = (const float*)d_in[9];
  const float* ad2 = (const float*)d_in[10];
  const float* b2  = (const float*)d_in[11];
  float* out = (float*)d_out;

  int N = in_sizes[0] / D_IN;   // 20000
  int E = in_sizes[1] / 2;      // 100000
  int Etot = E + N;             // 120000 (self-loops appended)

  float* ws = (float*)d_ws;
  size_t NF = (size_t)N * HC;
  float* asr1 = ws;                       // N*8  (plain-written in GEMM1)
  float* adt1 = asr1 + (size_t)N * NH1;   // N*8
  float* asr2 = adt1 + (size_t)N * NH1;   // N*8  (partials, plain-written GEMM2)
  float* adt2 = asr2 + (size_t)N * 2 * NH2; // N*8
  // ---- zero-init region: acc2, cnt, cursor (contiguous) ----
  float* acc2 = adt2 + (size_t)N * 2 * NH2; // 256
  int*   cnt    = (int*)(acc2 + 256);     // N
  int*   cursor = cnt + N;                // N (zeroed; also pads scan's int4 tail)
  size_t zero_bytes = (256 + 2 * (size_t)N) * sizeof(float);
  // ---- fully-written region ----
  int*   rowstart = cursor + N;           // N+1
  int*   csr_src  = rowstart + N + 1;     // Etot
  ushort* xpbf = (ushort*)((((uintptr_t)(csr_src + Etot)) + 15) & ~(uintptr_t)15);
  ushort* Abf = xpbf + NF;                // N*512
  ushort* Wt1 = Abf + NF;                 // 512*512
  ushort* Wt2 = Wt1 + (size_t)D_IN * HC;  // 512*512

  hipMemsetAsync(acc2, 0, zero_bytes, stream);

  // casts (x) + W tile-transpose + degree histogram in one launch
  int n4x = (int)(NF / 4);
  int nxb = (n4x + 255) / 256;
  int nhb = (Etot + 255) / 256;
  k_pre<<<nxb + 128 + nhb, 256, 0, stream>>>(x, Abf, W1, W2, Wt1, Wt2, n4x,
                                             ei, E, Etot, cnt);

  int nwg = (HC / BN) * ((N + BM - 1) / BM);  // 628
  int aggblocks = (N + 3) / 4;                // 4 nodes (waves) per block

  // ---- layer 1: gemm (blocks 1..628) + CSR scan (block 0) in one launch ----
  k_gemm_bf16<NH1, 1><<<nwg + 1, 256, 0, stream>>>(Abf, Wt1, xpbf, as1, ad1, asr1, adt1, N,
                                                   cnt, rowstart, N);
  k_scatter<<<(Etot + 255) / 256, 256, 0, stream>>>(ei, E, Etot, rowstart, cursor, csr_src);
  k_agg<NH1, 1><<<aggblocks, 256, 0, stream>>>(rowstart, csr_src, asr1, adt1, xpbf, Abf,
                                               nullptr, b1, nullptr, nullptr, nullptr, N);

  // ---- layer 2 ----
  k_gemm_bf16<NH2, 0><<<nwg, 256, 0, stream>>>(Abf, Wt2, xpbf, as2, ad2, asr2, adt2, N,
                                               nullptr, nullptr, N);
  k_agg<NH2, 2><<<aggblocks, 256, 0, stream>>>(rowstart, csr_src, asr2, adt2, xpbf, nullptr,
                                               out + 1, b2, y, msk, acc2, N);

  // ---- epilogue: loss ----
  k_final<<<1, 128, 0, stream>>>(acc2, out);
}